// Round 13
// baseline (674.582 us; speedup 1.0000x reference)
//
#include <hip/hip_runtime.h>
#include <hip/hip_bf16.h>
#include <hip/hip_fp16.h>
#include <math.h>

// ---------------------------------------------------------------------------
// ChaosSSMCore: selective diag-SSM
//   B=128, T=2048, D=256, M = B*T = 262144
//   delta = softplus(x @ Wd^T); decay = exp(-delta*exp(log_a))
//   update = delta * sigmoid(x @ Ws^T) * (x @ Wi^T)
//   states = scan(decay, update);  y = states * silu(x @ Wg^T)
//   out = y @ Wo^T
// ---------------------------------------------------------------------------

typedef __attribute__((ext_vector_type(8))) short s16x8;
typedef __attribute__((ext_vector_type(4))) float f32x4;

#define D_DIM 256
#define T_DIM 2048
#define B_DIM 128
#define NCHUNK2 32               // half-chunks of 64 timesteps
#define CLEN 128                 // full chunk (scan_out tile)

__device__ __forceinline__ unsigned short f2bf(float f) {
    union { float f; unsigned int u; } v; v.f = f;
    unsigned int r = v.u + 0x7fffu + ((v.u >> 16) & 1u);   // RNE
    return (unsigned short)(r >> 16);
}
__device__ __forceinline__ float bf2f(unsigned short s) {
    union { unsigned int u; float f; } v; v.u = ((unsigned int)s) << 16;
    return v.f;
}
__device__ __forceinline__ void gload_lds16(const void* g, void* l) {
    __builtin_amdgcn_global_load_lds(
        (const __attribute__((address_space(1))) unsigned int*)g,
        (__attribute__((address_space(3))) unsigned int*)l, 16, 0, 0);
}

// --------------------------- prep: build Wcat + Wo + ea --------------------
// Wcat[1024][256] bf16, row = n*4 + w, w: 0=delta 1=select 2=in 3=gate.
// Wo slab at +4*65536 (plain [256][256]). ea = exp(log_a).
__global__ __launch_bounds__(256) void prep_kernel(
    const float* __restrict__ W_in, const float* __restrict__ W_select,
    const float* __restrict__ W_gate, const float* __restrict__ W_out,
    const float* __restrict__ W_delta, const float* __restrict__ log_a,
    unsigned short* __restrict__ Wb, float* __restrict__ ea)
{
    int i = blockIdx.x * 256 + threadIdx.x;
    if (i < 4 * 65536) {
        int row = i >> 8, k = i & 255;
        int n = row >> 2, w = row & 3;
        const float* src = (w == 0) ? W_delta : (w == 1) ? W_select
                         : (w == 2) ? W_in    : W_gate;
        Wb[i] = f2bf(src[n * 256 + k]);
    } else if (i < 5 * 65536) {
        Wb[i] = f2bf(W_out[i - 4 * 65536]);
    } else if (i < 5 * 65536 + 256) {
        int j = i - 5 * 65536;
        ea[j] = expf(log_a[j]);
    }
}

// --------------------------- xcast: x fp32 -> bf16 -------------------------
__global__ __launch_bounds__(256) void xcast_kernel(
    const float* __restrict__ x, unsigned short* __restrict__ xb)
{
    size_t i = ((size_t)blockIdx.x * 256 + threadIdx.x) * 8;
    float4 p0 = *(const float4*)(x + i);
    float4 p1 = *(const float4*)(x + i + 4);
    s16x8 a;
    a[0] = (short)f2bf(p0.x); a[1] = (short)f2bf(p0.y);
    a[2] = (short)f2bf(p0.z); a[3] = (short)f2bf(p0.w);
    a[4] = (short)f2bf(p1.x); a[5] = (short)f2bf(p1.y);
    a[6] = (short)f2bf(p1.z); a[7] = (short)f2bf(p1.w);
    *(s16x8*)(xb + i) = a;
}

// --------------------------- gemm_fused v5: counted-vmcnt dbuf -------------
// Block = 128m x 128 Wcat-rows (32 n x 4 W), 4 waves 2x2 (wave 64x64).
// BK=32, double-buffered 2 x 16 KB (A 8K + B 8K per buf, total 32 KB LDS).
// Per step: issue 4 prefetch global_load_lds into buf^1, s_waitcnt vmcnt(4)
// (prev step's loads done, prefetch stays IN FLIGHT across the barrier),
// raw s_barrier, 8 ds_read_b128 + 16 MFMA from buf, lgkmcnt(0), s_barrier.
// 64B-row granule swizzle g' = g ^ ((row>>1)&3): bank = (row&1)*16 + g'*4,
// same-parity lanes spread over 4 granule groups -> 2-way (free).
// Fused scan1 epilogue (in-register butterfly) exactly as round 12.
__global__ __launch_bounds__(256, 3) void gemm_fused_kernel(
    const unsigned short* __restrict__ xb, const unsigned short* __restrict__ Wcat,
    const float* __restrict__ ea,
    __half2* __restrict__ du, unsigned short* __restrict__ gate,
    float* __restrict__ cA, float* __restrict__ cS)
{
    __shared__ char lds[32768];    // buf0: A[0,8K) B[8K,16K); buf1: +16K
    int bid = blockIdx.x;
    int wg  = (bid & 7) * 2048 + (bid >> 3);   // XCD chunk swizzle (16384%8==0)
    int mt  = wg >> 3;                          // = b*16 + c (chunk of 128 t)
    int nt  = wg & 7;
    int mbase = mt * 128;
    int nb = nt * 128;                          // Wcat row base
    int tid = threadIdx.x, lane = tid & 63, wid = tid >> 6;
    int l16 = lane & 15, lk = lane >> 4;
    int wr = wid >> 1, wc = wid & 1;

    const unsigned short* xg  = xb   + (size_t)mbase * D_DIM;
    const unsigned short* wgp = Wcat + (size_t)nb * D_DIM;

    // staging slots: 512 granules per operand, 2 per thread
    int se0 = tid, se1 = 256 + tid;
    int sr0 = se0 >> 2, sg0 = (se0 & 3) ^ ((sr0 >> 1) & 3);
    int sr1 = se1 >> 2, sg1 = (se1 & 3) ^ ((sr1 >> 1) & 3);

    // preload epilogue constants, then drain VMEM so vmcnt counting is exact
    float eav[4];
#pragma unroll
    for (int nf = 0; nf < 4; ++nf)
        eav[nf] = ea[nt * 32 + wc * 16 + nf * 4 + lk];
    asm volatile("s_waitcnt vmcnt(0)" ::: "memory");
    __builtin_amdgcn_sched_barrier(0);

#define STAGE(BUFB, KB)                                                     \
    {                                                                        \
        gload_lds16(xg  + (size_t)sr0 * D_DIM + (KB) + sg0 * 8,              \
                    lds + (BUFB) + se0 * 16);                                \
        gload_lds16(xg  + (size_t)sr1 * D_DIM + (KB) + sg1 * 8,              \
                    lds + (BUFB) + se1 * 16);                                \
        gload_lds16(wgp + (size_t)sr0 * D_DIM + (KB) + sg0 * 8,              \
                    lds + (BUFB) + 8192 + se0 * 16);                         \
        gload_lds16(wgp + (size_t)sr1 * D_DIM + (KB) + sg1 * 8,              \
                    lds + (BUFB) + 8192 + se1 * 16);                         \
    }

    f32x4 acc[4][4] = {};           // [mf][nf]

#define COMPUTE(BUFB)                                                        \
    {                                                                        \
        s16x8 xf[4], wf[4];                                                  \
        _Pragma("unroll")                                                    \
        for (int mf = 0; mf < 4; ++mf) {                                     \
            int row = wr * 64 + mf * 16 + l16;                               \
            int g = lk ^ ((row >> 1) & 3);                                   \
            xf[mf] = *(const s16x8*)(lds + (BUFB) + row * 64 + g * 16);      \
        }                                                                    \
        _Pragma("unroll")                                                    \
        for (int nf = 0; nf < 4; ++nf) {                                     \
            int row = wc * 64 + nf * 16 + l16;                               \
            int g = lk ^ ((row >> 1) & 3);                                   \
            wf[nf] = *(const s16x8*)(lds + (BUFB) + 8192 + row * 64 + g * 16);\
        }                                                                    \
        _Pragma("unroll")                                                    \
        for (int nf = 0; nf < 4; ++nf)                                       \
            _Pragma("unroll")                                                \
            for (int mf = 0; mf < 4; ++mf)                                   \
                acc[mf][nf] = __builtin_amdgcn_mfma_f32_16x16x32_bf16(       \
                    wf[nf], xf[mf], acc[mf][nf], 0, 0, 0);                   \
    }

    STAGE(0, 0);                    // prologue: step 0 -> buf0
#pragma unroll 1
    for (int p = 0; p < 4; ++p) {
        // ---- first half: compute step 2p (buf0), stage step 2p+1 -> buf1
        STAGE(16384, (2 * p + 1) * 32);
        __builtin_amdgcn_sched_barrier(0);
        asm volatile("s_waitcnt vmcnt(4)" ::: "memory");
        __builtin_amdgcn_s_barrier();
        __builtin_amdgcn_sched_barrier(0);
        COMPUTE(0);
        __builtin_amdgcn_sched_barrier(0);
        asm volatile("s_waitcnt lgkmcnt(0)" ::: "memory");
        __builtin_amdgcn_s_barrier();
        __builtin_amdgcn_sched_barrier(0);
        // ---- second half: compute step 2p+1 (buf1), stage 2p+2 -> buf0
        if (p < 3) {
            STAGE(0, (2 * p + 2) * 32);
            __builtin_amdgcn_sched_barrier(0);
            asm volatile("s_waitcnt vmcnt(4)" ::: "memory");
        } else {
            __builtin_amdgcn_sched_barrier(0);
            asm volatile("s_waitcnt vmcnt(0)" ::: "memory");
        }
        __builtin_amdgcn_s_barrier();
        __builtin_amdgcn_sched_barrier(0);
        COMPUTE(16384);
        __builtin_amdgcn_sched_barrier(0);
        asm volatile("s_waitcnt lgkmcnt(0)" ::: "memory");
        __builtin_amdgcn_s_barrier();
        __builtin_amdgcn_sched_barrier(0);
    }
#undef STAGE
#undef COMPUTE

    // ---- epilogue: acc[mf][nf] = {z_delta, z_select, z_in, z_gate}(m,n) ----
    // plus in-register half-chunk scan summaries (butterfly over l16).
#pragma unroll
    for (int nf = 0; nf < 4; ++nf) {
        int n = nt * 32 + wc * 16 + nf * 4 + lk;
        float ean = eav[nf];
        float A[4], S[4];
#pragma unroll
        for (int mf = 0; mf < 4; ++mf) {
            int m = mbase + wr * 64 + mf * 16 + l16;
            float zd = acc[mf][nf][0];
            float zs = acc[mf][nf][1];
            float zi = acc[mf][nf][2];
            float zg = acc[mf][nf][3];
            float e = __expf(zd);
            float delta = (zd > 15.f) ? zd : __logf(1.f + e);
            float dec = __expf(-delta * ean);
            float sel = 1.f / (1.f + __expf(-zs));
            float upd = delta * sel * zi;
            float g   = zg / (1.f + __expf(-zg));   // silu
            du[(size_t)m * D_DIM + n] = __floats2half2_rn(dec, upd);
            gate[(size_t)m * D_DIM + n] = f2bf(g);
            A[mf] = dec;
            S[mf] = upd;
        }
        // 16-lane butterfly compose over l16 (t-order = l16 within mf-block)
#pragma unroll
        for (int d = 1; d < 16; d <<= 1) {
            bool upper = (l16 & d);
#pragma unroll
            for (int mf = 0; mf < 4; ++mf) {
                float Ap = __shfl_xor(A[mf], d, 64);
                float Sp = __shfl_xor(S[mf], d, 64);
                float Se = upper ? Sp : S[mf];
                float Al = upper ? A[mf] : Ap;
                float Sl = upper ? S[mf] : Sp;
                S[mf] = fmaf(Al, Se, Sl);
                A[mf] = A[mf] * Ap;
            }
        }
        // in-thread compose across mf (t ascending: mf-blocks of 16)
        float cAe = A[0], cSe = S[0];
#pragma unroll
        for (int mf = 1; mf < 4; ++mf) {
            cSe = fmaf(A[mf], cSe, S[mf]);
            cAe *= A[mf];
        }
        if (l16 == 0) {
            int hc = mt * 2 + wr;          // = b*32 + (c*2 + wr)
            cA[hc * D_DIM + n] = cAe;
            cS[hc * D_DIM + n] = cSe;
        }
    }
}

// --------------------------- scan pass 2: half-chunk carries ---------------
__global__ __launch_bounds__(256) void scan2_kernel(
    const float* __restrict__ cA, const float* __restrict__ cS,
    float* __restrict__ carry)
{
    int b = blockIdx.x;
    int d = threadIdx.x;
    float s = 0.f;
    for (int c = 0; c < NCHUNK2; ++c) {
        int idx = (b * NCHUNK2 + c) * D_DIM + d;
        carry[idx] = s;                 // state entering half-chunk c
        s = fmaf(cA[idx], s, cS[idx]);
    }
}

// --------------------------- fused scan3 + out-projection ------------------
// block = (b, chunk of 128): scans 128 t-rows (full D), builds y tile in LDS
// (bf16, chunk-XOR-swizzled), then computes out[128 x 256] = y @ Wo^T.
__global__ __launch_bounds__(256) void scan_out_kernel(
    const __half2* __restrict__ du, const unsigned short* __restrict__ gate,
    const float* __restrict__ carry, const unsigned short* __restrict__ Wo,
    float* __restrict__ out)
{
    __shared__ unsigned short yls[128 * 256];   // 64 KB
    int b = blockIdx.x >> 4;
    int c = blockIdx.x & 15;
    int tid = threadIdx.x;

    // ---- phase 1: sequential scan, y -> LDS (swizzled 16B chunks) ----
    {
        int d = tid;
        size_t base = ((size_t)b * T_DIM + (size_t)c * CLEN) * D_DIM + d;
        float s = carry[(b * NCHUNK2 + c * 2) * D_DIM + d];
        int dlo = d & 7, dch = d >> 3;
#pragma unroll 4
        for (int t = 0; t < CLEN; ++t) {
            __half2 v = du[base + (size_t)t * D_DIM];
            float dc = __low2float(v);
            float up = __high2float(v);
            s = fmaf(dc, s, up);
            float g = bf2f(gate[base + (size_t)t * D_DIM]);
            int off = t * 256 + ((dch ^ (t & 7)) << 3) + dlo;
            yls[off] = f2bf(s * g);
        }
    }
    __syncthreads();

    // ---- phase 2: out-tile GEMM, A-frag = Wo rows (global), B-frag = y (LDS)
    int lane = tid & 63, wid = tid >> 6;
    int l16 = lane & 15;
    int lkc = lane >> 4;            // k-subgroup 0..3
    int m0 = (wid >> 1) * 64;
    size_t rbase = (size_t)b * T_DIM + (size_t)c * CLEN;
    int r0 = lkc * 4;

    for (int nblk = 0; nblk < 2; ++nblk) {
        int n0 = (wid & 1) * 64 + nblk * 128;
        f32x4 acc[4][4] = {};
        for (int ks = 0; ks < 8; ++ks) {
            int kb = ks * 32 + lkc * 8;
            s16x8 yf[4];
#pragma unroll
            for (int mf = 0; mf < 4; ++mf) {
                int row = m0 + mf * 16 + l16;
                int chunk = (ks * 4 + lkc) ^ (row & 7);
                yf[mf] = *(const s16x8*)&yls[row * 256 + chunk * 8];
            }
#pragma unroll
            for (int nf = 0; nf < 4; ++nf) {
                s16x8 wfr = *(const s16x8*)(Wo + (size_t)(n0 + nf * 16 + l16) * D_DIM + kb);
#pragma unroll
                for (int mf = 0; mf < 4; ++mf)
                    acc[mf][nf] = __builtin_amdgcn_mfma_f32_16x16x32_bf16(
                        wfr, yf[mf], acc[mf][nf], 0, 0, 0);
            }
        }
        // D col = lane&15 = y row; D rows = n (4 consecutive) -> float4 stores
#pragma unroll
        for (int mf = 0; mf < 4; ++mf) {
            size_t rowg = rbase + m0 + mf * 16 + l16;
#pragma unroll
            for (int nf = 0; nf < 4; ++nf) {
                int n = n0 + nf * 16 + r0;
                *(f32x4*)(out + rowg * D_DIM + n) = acc[mf][nf];
            }
        }
    }
}

// ---------------------------------------------------------------------------
extern "C" void kernel_launch(void* const* d_in, const int* in_sizes, int n_in,
                              void* d_out, int out_size, void* d_ws, size_t ws_size,
                              hipStream_t stream)
{
    const float* x        = (const float*)d_in[0];
    const float* W_in     = (const float*)d_in[1];
    const float* W_select = (const float*)d_in[2];
    const float* W_gate   = (const float*)d_in[3];
    const float* W_out    = (const float*)d_in[4];
    const float* W_delta  = (const float*)d_in[5];
    const float* log_a    = (const float*)d_in[6];
    float* out = (float*)d_out;

    char* ws = (char*)d_ws;
    const size_t MB = 1ull << 20;
    unsigned short* Wb    = (unsigned short*)(ws);               // 640 KB
    float*          ea    = (float*)(ws + 655360);               // 1 KB
    unsigned short* xb    = (unsigned short*)(ws + 1 * MB);      // 128 MB
    __half2*        du    = (__half2*)(ws + 129 * MB);           // 256 MB
    unsigned short* gate  = (unsigned short*)(ws + 385 * MB);    // 128 MB
    float*          cA    = (float*)(ws + 513 * MB);             // 4 MB
    float*          cS    = (float*)(ws + 517 * MB);             // 4 MB
    float*          carry = (float*)(ws + 521 * MB);             // 4 MB
    // total: 525 MB

    prep_kernel<<<1281, 256, 0, stream>>>(W_in, W_select, W_gate, W_out,
                                          W_delta, log_a, Wb, ea);
    xcast_kernel<<<32768, 256, 0, stream>>>(x, xb);
    gemm_fused_kernel<<<16384, 256, 0, stream>>>(xb, Wb, ea, du, gate, cA, cS);
    scan2_kernel<<<B_DIM, 256, 0, stream>>>(cA, cS, carry);
    scan_out_kernel<<<B_DIM * NCHUNK2 / 2, 256, 0, stream>>>(du, gate, carry,
                                                             Wb + 4 * 65536, out);
}

// Round 14
// 671.795 us; speedup vs baseline: 1.0041x; 1.0041x over previous
//
#include <hip/hip_runtime.h>
#include <hip/hip_bf16.h>
#include <hip/hip_fp16.h>
#include <math.h>

// ---------------------------------------------------------------------------
// ChaosSSMCore: selective diag-SSM
//   B=128, T=2048, D=256, M = B*T = 262144
//   delta = softplus(x @ Wd^T); decay = exp(-delta*exp(log_a))
//   update = delta * sigmoid(x @ Ws^T) * (x @ Wi^T)
//   states = scan(decay, update);  y = states * silu(x @ Wg^T)
//   out = y @ Wo^T
// ---------------------------------------------------------------------------

typedef __attribute__((ext_vector_type(8))) short s16x8;
typedef __attribute__((ext_vector_type(4))) float f32x4;

#define D_DIM 256
#define T_DIM 2048
#define B_DIM 128
#define NCHUNK2 32               // half-chunks of 64 timesteps
#define CLEN 128                 // full chunk (scan_out tile)

__device__ __forceinline__ unsigned short f2bf(float f) {
    union { float f; unsigned int u; } v; v.f = f;
    unsigned int r = v.u + 0x7fffu + ((v.u >> 16) & 1u);   // RNE
    return (unsigned short)(r >> 16);
}
__device__ __forceinline__ float bf2f(unsigned short s) {
    union { unsigned int u; float f; } v; v.u = ((unsigned int)s) << 16;
    return v.f;
}
__device__ __forceinline__ void gload_lds16(const void* g, void* l) {
    __builtin_amdgcn_global_load_lds(
        (const __attribute__((address_space(1))) unsigned int*)g,
        (__attribute__((address_space(3))) unsigned int*)l, 16, 0, 0);
}

// --------------------------- prep: build Wcat + Wo + ea --------------------
// Wcat[1024][256] bf16, row = n*4 + w, w: 0=delta 1=select 2=in 3=gate.
// Wo slab at +4*65536 (plain [256][256]). ea = exp(log_a).
__global__ __launch_bounds__(256) void prep_kernel(
    const float* __restrict__ W_in, const float* __restrict__ W_select,
    const float* __restrict__ W_gate, const float* __restrict__ W_out,
    const float* __restrict__ W_delta, const float* __restrict__ log_a,
    unsigned short* __restrict__ Wb, float* __restrict__ ea)
{
    int i = blockIdx.x * 256 + threadIdx.x;
    if (i < 4 * 65536) {
        int row = i >> 8, k = i & 255;
        int n = row >> 2, w = row & 3;
        const float* src = (w == 0) ? W_delta : (w == 1) ? W_select
                         : (w == 2) ? W_in    : W_gate;
        Wb[i] = f2bf(src[n * 256 + k]);
    } else if (i < 5 * 65536) {
        Wb[i] = f2bf(W_out[i - 4 * 65536]);
    } else if (i < 5 * 65536 + 256) {
        int j = i - 5 * 65536;
        ea[j] = expf(log_a[j]);
    }
}

// --------------------------- xcast: x fp32 -> bf16 -------------------------
__global__ __launch_bounds__(256) void xcast_kernel(
    const float* __restrict__ x, unsigned short* __restrict__ xb)
{
    size_t i = ((size_t)blockIdx.x * 256 + threadIdx.x) * 8;
    float4 p0 = *(const float4*)(x + i);
    float4 p1 = *(const float4*)(x + i + 4);
    s16x8 a;
    a[0] = (short)f2bf(p0.x); a[1] = (short)f2bf(p0.y);
    a[2] = (short)f2bf(p0.z); a[3] = (short)f2bf(p0.w);
    a[4] = (short)f2bf(p1.x); a[5] = (short)f2bf(p1.y);
    a[6] = (short)f2bf(p1.z); a[7] = (short)f2bf(p1.w);
    *(s16x8*)(xb + i) = a;
}

// --------------------------- gemm_fused v6: 3-buf depth-2 vmcnt pipeline ---
// Block = 128m x 128 Wcat-rows (32 n x 4 W), 4 waves 2x2 (wave 64x64).
// BK=32, TRIPLE-buffered 3 x 16 KB = 48 KB (3 blocks/CU). Depth-2 prefetch:
// step s issues STAGE(s+2), then waits vmcnt(8) -> targets the stage issued
// TWO compute phases earlier (~400+ cyc cover). s_setprio(1) around MFMAs.
// 64B-row granule swizzle g' = g ^ ((row>>1)&3) (R13-verified, 0 conflicts).
// Fused scan1 epilogue (in-register butterfly) exactly as round 12.
__global__ __launch_bounds__(256, 3) void gemm_fused_kernel(
    const unsigned short* __restrict__ xb, const unsigned short* __restrict__ Wcat,
    const float* __restrict__ ea,
    __half2* __restrict__ du, unsigned short* __restrict__ gate,
    float* __restrict__ cA, float* __restrict__ cS)
{
    __shared__ char lds[49152];    // buf k at k*16384: A[0,8K) B[8K,16K)
    int bid = blockIdx.x;
    int wg  = (bid & 7) * 2048 + (bid >> 3);   // XCD chunk swizzle (16384%8==0)
    int mt  = wg >> 3;                          // = b*16 + c (chunk of 128 t)
    int nt  = wg & 7;
    int mbase = mt * 128;
    int nb = nt * 128;                          // Wcat row base
    int tid = threadIdx.x, lane = tid & 63, wid = tid >> 6;
    int l16 = lane & 15, lk = lane >> 4;
    int wr = wid >> 1, wc = wid & 1;

    const unsigned short* xg  = xb   + (size_t)mbase * D_DIM;
    const unsigned short* wgp = Wcat + (size_t)nb * D_DIM;

    // staging slots: 512 granules per operand, 2 per thread
    int se0 = tid, se1 = 256 + tid;
    int sr0 = se0 >> 2, sg0 = (se0 & 3) ^ ((sr0 >> 1) & 3);
    int sr1 = se1 >> 2, sg1 = (se1 & 3) ^ ((sr1 >> 1) & 3);

    // hoisted LDS read offsets (loop-invariant)
    int xoff[4], woff[4];
#pragma unroll
    for (int mf = 0; mf < 4; ++mf) {
        int row = wr * 64 + mf * 16 + l16;
        xoff[mf] = row * 64 + (lk ^ ((row >> 1) & 3)) * 16;
    }
#pragma unroll
    for (int nf = 0; nf < 4; ++nf) {
        int row = wc * 64 + nf * 16 + l16;
        woff[nf] = 8192 + row * 64 + (lk ^ ((row >> 1) & 3)) * 16;
    }

    // preload epilogue constants, then drain VMEM so vmcnt counting is exact
    float eav[4];
#pragma unroll
    for (int nf = 0; nf < 4; ++nf)
        eav[nf] = ea[nt * 32 + wc * 16 + nf * 4 + lk];
    asm volatile("s_waitcnt vmcnt(0)" ::: "memory");
    __builtin_amdgcn_sched_barrier(0);

#define STAGE(BUFB, KB)                                                      \
    {                                                                        \
        gload_lds16(xg  + (size_t)sr0 * D_DIM + (KB) + sg0 * 8,              \
                    lds + (BUFB) + se0 * 16);                                \
        gload_lds16(xg  + (size_t)sr1 * D_DIM + (KB) + sg1 * 8,              \
                    lds + (BUFB) + se1 * 16);                                \
        gload_lds16(wgp + (size_t)sr0 * D_DIM + (KB) + sg0 * 8,              \
                    lds + (BUFB) + 8192 + se0 * 16);                         \
        gload_lds16(wgp + (size_t)sr1 * D_DIM + (KB) + sg1 * 8,              \
                    lds + (BUFB) + 8192 + se1 * 16);                         \
    }

    f32x4 acc[4][4] = {};           // [mf][nf]

#define COMPUTE(BUFB)                                                        \
    {                                                                        \
        s16x8 xf[4], wf[4];                                                  \
        _Pragma("unroll")                                                    \
        for (int mf = 0; mf < 4; ++mf)                                       \
            xf[mf] = *(const s16x8*)(lds + (BUFB) + xoff[mf]);               \
        _Pragma("unroll")                                                    \
        for (int nf = 0; nf < 4; ++nf)                                       \
            wf[nf] = *(const s16x8*)(lds + (BUFB) + woff[nf]);               \
        __builtin_amdgcn_s_setprio(1);                                       \
        _Pragma("unroll")                                                    \
        for (int nf = 0; nf < 4; ++nf)                                       \
            _Pragma("unroll")                                                \
            for (int mf = 0; mf < 4; ++mf)                                   \
                acc[mf][nf] = __builtin_amdgcn_mfma_f32_16x16x32_bf16(       \
                    wf[nf], xf[mf], acc[mf][nf], 0, 0, 0);                   \
        __builtin_amdgcn_s_setprio(0);                                       \
    }

#define SYNC_IN(VMSTR)                                                       \
    __builtin_amdgcn_sched_barrier(0);                                       \
    asm volatile("s_waitcnt vmcnt(" VMSTR ")" ::: "memory");                 \
    __builtin_amdgcn_s_barrier();                                            \
    __builtin_amdgcn_sched_barrier(0);

#define SYNC_OUT                                                             \
    __builtin_amdgcn_sched_barrier(0);                                       \
    asm volatile("s_waitcnt lgkmcnt(0)" ::: "memory");                       \
    __builtin_amdgcn_s_barrier();                                            \
    __builtin_amdgcn_sched_barrier(0);

    // prologue: stage steps 0,1 -> buf0,buf1
    STAGE(0, 0);
    STAGE(16384, 32);
    // step 0..7 (BK=32); buf = s%3; stage(s+2) -> buf (s+2)%3
    STAGE(32768, 64);   SYNC_IN("8")  COMPUTE(0)      SYNC_OUT   // s=0
    STAGE(0, 96);       SYNC_IN("8")  COMPUTE(16384)  SYNC_OUT   // s=1
    STAGE(16384, 128);  SYNC_IN("8")  COMPUTE(32768)  SYNC_OUT   // s=2
    STAGE(32768, 160);  SYNC_IN("8")  COMPUTE(0)      SYNC_OUT   // s=3
    STAGE(0, 192);      SYNC_IN("8")  COMPUTE(16384)  SYNC_OUT   // s=4
    STAGE(16384, 224);  SYNC_IN("8")  COMPUTE(32768)  SYNC_OUT   // s=5
                        SYNC_IN("4")  COMPUTE(0)      SYNC_OUT   // s=6
                        SYNC_IN("0")  COMPUTE(16384)  SYNC_OUT   // s=7
#undef STAGE
#undef COMPUTE
#undef SYNC_IN
#undef SYNC_OUT

    // ---- epilogue: acc[mf][nf] = {z_delta, z_select, z_in, z_gate}(m,n) ----
    // plus in-register half-chunk scan summaries (butterfly over l16).
#pragma unroll
    for (int nf = 0; nf < 4; ++nf) {
        int n = nt * 32 + wc * 16 + nf * 4 + lk;
        float ean = eav[nf];
        float A[4], S[4];
#pragma unroll
        for (int mf = 0; mf < 4; ++mf) {
            int m = mbase + wr * 64 + mf * 16 + l16;
            float zd = acc[mf][nf][0];
            float zs = acc[mf][nf][1];
            float zi = acc[mf][nf][2];
            float zg = acc[mf][nf][3];
            float e = __expf(zd);
            float delta = (zd > 15.f) ? zd : __logf(1.f + e);
            float dec = __expf(-delta * ean);
            float sel = 1.f / (1.f + __expf(-zs));
            float upd = delta * sel * zi;
            float g   = zg / (1.f + __expf(-zg));   // silu
            du[(size_t)m * D_DIM + n] = __floats2half2_rn(dec, upd);
            gate[(size_t)m * D_DIM + n] = f2bf(g);
            A[mf] = dec;
            S[mf] = upd;
        }
        // 16-lane butterfly compose over l16 (t-order = l16 within mf-block)
#pragma unroll
        for (int d = 1; d < 16; d <<= 1) {
            bool upper = (l16 & d);
#pragma unroll
            for (int mf = 0; mf < 4; ++mf) {
                float Ap = __shfl_xor(A[mf], d, 64);
                float Sp = __shfl_xor(S[mf], d, 64);
                float Se = upper ? Sp : S[mf];
                float Al = upper ? A[mf] : Ap;
                float Sl = upper ? S[mf] : Sp;
                S[mf] = fmaf(Al, Se, Sl);
                A[mf] = A[mf] * Ap;
            }
        }
        // in-thread compose across mf (t ascending: mf-blocks of 16)
        float cAe = A[0], cSe = S[0];
#pragma unroll
        for (int mf = 1; mf < 4; ++mf) {
            cSe = fmaf(A[mf], cSe, S[mf]);
            cAe *= A[mf];
        }
        if (l16 == 0) {
            int hc = mt * 2 + wr;          // = b*32 + (c*2 + wr)
            cA[hc * D_DIM + n] = cAe;
            cS[hc * D_DIM + n] = cSe;
        }
    }
}

// --------------------------- scan pass 2: half-chunk carries ---------------
__global__ __launch_bounds__(256) void scan2_kernel(
    const float* __restrict__ cA, const float* __restrict__ cS,
    float* __restrict__ carry)
{
    int b = blockIdx.x;
    int d = threadIdx.x;
    float s = 0.f;
    for (int c = 0; c < NCHUNK2; ++c) {
        int idx = (b * NCHUNK2 + c) * D_DIM + d;
        carry[idx] = s;                 // state entering half-chunk c
        s = fmaf(cA[idx], s, cS[idx]);
    }
}

// --------------------------- fused scan3 + out-projection ------------------
// block = (b, chunk of 128): scans 128 t-rows (full D), builds y tile in LDS
// (bf16, chunk-XOR-swizzled), then computes out[128 x 256] = y @ Wo^T.
__global__ __launch_bounds__(256) void scan_out_kernel(
    const __half2* __restrict__ du, const unsigned short* __restrict__ gate,
    const float* __restrict__ carry, const unsigned short* __restrict__ Wo,
    float* __restrict__ out)
{
    __shared__ unsigned short yls[128 * 256];   // 64 KB
    int b = blockIdx.x >> 4;
    int c = blockIdx.x & 15;
    int tid = threadIdx.x;

    // ---- phase 1: sequential scan, y -> LDS (swizzled 16B chunks) ----
    {
        int d = tid;
        size_t base = ((size_t)b * T_DIM + (size_t)c * CLEN) * D_DIM + d;
        float s = carry[(b * NCHUNK2 + c * 2) * D_DIM + d];
        int dlo = d & 7, dch = d >> 3;
#pragma unroll 4
        for (int t = 0; t < CLEN; ++t) {
            __half2 v = du[base + (size_t)t * D_DIM];
            float dc = __low2float(v);
            float up = __high2float(v);
            s = fmaf(dc, s, up);
            float g = bf2f(gate[base + (size_t)t * D_DIM]);
            int off = t * 256 + ((dch ^ (t & 7)) << 3) + dlo;
            yls[off] = f2bf(s * g);
        }
    }
    __syncthreads();

    // ---- phase 2: out-tile GEMM, A-frag = Wo rows (global), B-frag = y (LDS)
    int lane = tid & 63, wid = tid >> 6;
    int l16 = lane & 15;
    int lkc = lane >> 4;            // k-subgroup 0..3
    int m0 = (wid >> 1) * 64;
    size_t rbase = (size_t)b * T_DIM + (size_t)c * CLEN;
    int r0 = lkc * 4;

    for (int nblk = 0; nblk < 2; ++nblk) {
        int n0 = (wid & 1) * 64 + nblk * 128;
        f32x4 acc[4][4] = {};
        for (int ks = 0; ks < 8; ++ks) {
            int kb = ks * 32 + lkc * 8;
            s16x8 yf[4];
#pragma unroll
            for (int mf = 0; mf < 4; ++mf) {
                int row = m0 + mf * 16 + l16;
                int chunk = (ks * 4 + lkc) ^ (row & 7);
                yf[mf] = *(const s16x8*)&yls[row * 256 + chunk * 8];
            }
#pragma unroll
            for (int nf = 0; nf < 4; ++nf) {
                s16x8 wfr = *(const s16x8*)(Wo + (size_t)(n0 + nf * 16 + l16) * D_DIM + kb);
#pragma unroll
                for (int mf = 0; mf < 4; ++mf)
                    acc[mf][nf] = __builtin_amdgcn_mfma_f32_16x16x32_bf16(
                        wfr, yf[mf], acc[mf][nf], 0, 0, 0);
            }
        }
        // D col = lane&15 = y row; D rows = n (4 consecutive) -> float4 stores
#pragma unroll
        for (int mf = 0; mf < 4; ++mf) {
            size_t rowg = rbase + m0 + mf * 16 + l16;
#pragma unroll
            for (int nf = 0; nf < 4; ++nf) {
                int n = n0 + nf * 16 + r0;
                *(f32x4*)(out + rowg * D_DIM + n) = acc[mf][nf];
            }
        }
    }
}

// ---------------------------------------------------------------------------
extern "C" void kernel_launch(void* const* d_in, const int* in_sizes, int n_in,
                              void* d_out, int out_size, void* d_ws, size_t ws_size,
                              hipStream_t stream)
{
    const float* x        = (const float*)d_in[0];
    const float* W_in     = (const float*)d_in[1];
    const float* W_select = (const float*)d_in[2];
    const float* W_gate   = (const float*)d_in[3];
    const float* W_out    = (const float*)d_in[4];
    const float* W_delta  = (const float*)d_in[5];
    const float* log_a    = (const float*)d_in[6];
    float* out = (float*)d_out;

    char* ws = (char*)d_ws;
    const size_t MB = 1ull << 20;
    unsigned short* Wb    = (unsigned short*)(ws);               // 640 KB
    float*          ea    = (float*)(ws + 655360);               // 1 KB
    unsigned short* xb    = (unsigned short*)(ws + 1 * MB);      // 128 MB
    __half2*        du    = (__half2*)(ws + 129 * MB);           // 256 MB
    unsigned short* gate  = (unsigned short*)(ws + 385 * MB);    // 128 MB
    float*          cA    = (float*)(ws + 513 * MB);             // 4 MB
    float*          cS    = (float*)(ws + 517 * MB);             // 4 MB
    float*          carry = (float*)(ws + 521 * MB);             // 4 MB
    // total: 525 MB

    prep_kernel<<<1281, 256, 0, stream>>>(W_in, W_select, W_gate, W_out,
                                          W_delta, log_a, Wb, ea);
    xcast_kernel<<<32768, 256, 0, stream>>>(x, xb);
    gemm_fused_kernel<<<16384, 256, 0, stream>>>(xb, Wb, ea, du, gate, cA, cS);
    scan2_kernel<<<B_DIM, 256, 0, stream>>>(cA, cS, carry);
    scan_out_kernel<<<B_DIM * NCHUNK2 / 2, 256, 0, stream>>>(du, gate, carry,
                                                             Wb + 4 * 65536, out);
}

// Round 15
// 592.318 us; speedup vs baseline: 1.1389x; 1.1342x over previous
//
#include <hip/hip_runtime.h>
#include <hip/hip_bf16.h>
#include <hip/hip_fp16.h>
#include <math.h>

// ---------------------------------------------------------------------------
// ChaosSSMCore: selective diag-SSM
//   B=128, T=2048, D=256, M = B*T = 262144
//   delta = softplus(x @ Wd^T); decay = exp(-delta*exp(log_a))
//   update = delta * sigmoid(x @ Ws^T) * (x @ Wi^T)
//   states = scan(decay, update);  y = states * silu(x @ Wg^T)
//   out = y @ Wo^T
// ---------------------------------------------------------------------------

typedef __attribute__((ext_vector_type(8))) short s16x8;
typedef __attribute__((ext_vector_type(4))) float f32x4;

#define D_DIM 256
#define T_DIM 2048
#define B_DIM 128
#define NCHUNK2 32               // half-chunks of 64 timesteps
#define CLEN 128                 // full chunk (scan_out tile)
#define BK 64                    // GEMM K-step

__device__ __forceinline__ unsigned short f2bf(float f) {
    union { float f; unsigned int u; } v; v.f = f;
    unsigned int r = v.u + 0x7fffu + ((v.u >> 16) & 1u);   // RNE
    return (unsigned short)(r >> 16);
}
__device__ __forceinline__ float bf2f(unsigned short s) {
    union { unsigned int u; float f; } v; v.u = ((unsigned int)s) << 16;
    return v.f;
}
__device__ __forceinline__ void gload_lds16(const void* g, void* l) {
    __builtin_amdgcn_global_load_lds(
        (const __attribute__((address_space(1))) unsigned int*)g,
        (__attribute__((address_space(3))) unsigned int*)l, 16, 0, 0);
}

// --------------------------- prep: build Wcat + Wo + ea --------------------
// Wcat[1024][256] bf16, row = n*4 + w, w: 0=delta 1=select 2=in 3=gate.
// Wo slab at +4*65536 (plain [256][256]). ea = exp(log_a).
__global__ __launch_bounds__(256) void prep_kernel(
    const float* __restrict__ W_in, const float* __restrict__ W_select,
    const float* __restrict__ W_gate, const float* __restrict__ W_out,
    const float* __restrict__ W_delta, const float* __restrict__ log_a,
    unsigned short* __restrict__ Wb, float* __restrict__ ea)
{
    int i = blockIdx.x * 256 + threadIdx.x;
    if (i < 4 * 65536) {
        int row = i >> 8, k = i & 255;
        int n = row >> 2, w = row & 3;
        const float* src = (w == 0) ? W_delta : (w == 1) ? W_select
                         : (w == 2) ? W_in    : W_gate;
        Wb[i] = f2bf(src[n * 256 + k]);
    } else if (i < 5 * 65536) {
        Wb[i] = f2bf(W_out[i - 4 * 65536]);
    } else if (i < 5 * 65536 + 256) {
        int j = i - 5 * 65536;
        ea[j] = expf(log_a[j]);
    }
}

// --------------------------- xcast: x fp32 -> bf16 -------------------------
__global__ __launch_bounds__(256) void xcast_kernel(
    const float* __restrict__ x, unsigned short* __restrict__ xb)
{
    size_t i = ((size_t)blockIdx.x * 256 + threadIdx.x) * 8;
    float4 p0 = *(const float4*)(x + i);
    float4 p1 = *(const float4*)(x + i + 4);
    s16x8 a;
    a[0] = (short)f2bf(p0.x); a[1] = (short)f2bf(p0.y);
    a[2] = (short)f2bf(p0.z); a[3] = (short)f2bf(p0.w);
    a[4] = (short)f2bf(p1.x); a[5] = (short)f2bf(p1.y);
    a[6] = (short)f2bf(p1.z); a[7] = (short)f2bf(p1.w);
    *(s16x8*)(xb + i) = a;
}

// --------------------------- gemm_fused v7: coalesced-store epilogue -------
// K-loop identical to round 12 (best measured: 400us, 0 bank conflicts).
// Block = 128m x 128 Wcat-rows (32 n x 4 W), 4 waves 2x2 (wave 64x64).
// NEW: epilogue outputs go through an LDS transpose so global stores are
// full-128B-line writes (was: 64 distinct lines per store instruction,
// ~134M line transactions/dispatch = the ~400us plateau).
//   duT: half2, row stride 36 (144B, 16B-aligned)  [0, 18432)
//   gT : u16,   row stride 40 ( 80B, 16B-aligned)  [18432, 28672)
// Fused scan1 (in-register butterfly) unchanged.
__global__ __launch_bounds__(256, 3) void gemm_fused_kernel(
    const unsigned short* __restrict__ xb, const unsigned short* __restrict__ Wcat,
    const float* __restrict__ ea,
    __half2* __restrict__ du, unsigned short* __restrict__ gate,
    float* __restrict__ cA, float* __restrict__ cS)
{
    __shared__ char lds[32768];    // K-loop: A [0,16K), B [16K,32K); then tiles
    int bid = blockIdx.x;
    int wg  = (bid & 7) * 2048 + (bid >> 3);   // XCD chunk swizzle (16384%8==0)
    int mt  = wg >> 3;                          // = b*16 + c (chunk of 128 t)
    int nt  = wg & 7;
    int mbase = mt * 128;
    int nb = nt * 128;                          // Wcat row base
    int tid = threadIdx.x, lane = tid & 63, wid = tid >> 6;
    int l16 = lane & 15, lk = lane >> 4;
    int wr = wid >> 1, wc = wid & 1;
    int srow = tid >> 3;            // staging: 32 rows per issue-group
    int sgi  = tid & 7;             // staging granule (16B) within row

    f32x4 acc[4][4] = {};           // [mf][nf]

    for (int ks = 0; ks < 4; ++ks) {
        int kb = ks * BK;
        // ---- stage A (xb rows) and B (Wcat rows), pre-swizzled source ----
#pragma unroll
        for (int j = 0; j < 4; ++j) {
            int row = j * 32 + srow;
            int sg  = sgi ^ (row & 7);
            gload_lds16(xb + (size_t)(mbase + row) * D_DIM + kb + sg * 8,
                        lds + row * 128 + sgi * 16);
        }
#pragma unroll
        for (int j = 0; j < 4; ++j) {
            int row = j * 32 + srow;
            int sg  = sgi ^ (row & 7);
            gload_lds16(Wcat + (size_t)(nb + row) * D_DIM + kb + sg * 8,
                        lds + 16384 + row * 128 + sgi * 16);
        }
        __syncthreads();   // drains vmcnt -> staged data visible

        // ---- compute: 2 kk-halves, 8 ds_read + 16 MFMA each ----
#pragma unroll
        for (int kk = 0; kk < 2; ++kk) {
            int gp = ((kk * 4 + lk) ^ (l16 & 7)) * 16;   // swizzled granule
            s16x8 xf[4], wf[4];
#pragma unroll
            for (int mf = 0; mf < 4; ++mf)
                xf[mf] = *(const s16x8*)(lds
                           + (wr * 64 + mf * 16 + l16) * 128 + gp);
#pragma unroll
            for (int nf = 0; nf < 4; ++nf)
                wf[nf] = *(const s16x8*)(lds + 16384
                           + (wc * 64 + nf * 16 + l16) * 128 + gp);
#pragma unroll
            for (int nf = 0; nf < 4; ++nf)
#pragma unroll
                for (int mf = 0; mf < 4; ++mf)
                    acc[mf][nf] = __builtin_amdgcn_mfma_f32_16x16x32_bf16(
                        wf[nf], xf[mf], acc[mf][nf], 0, 0, 0);
        }
        __syncthreads();   // all reads done before next stage / LDS reuse
    }

    // ---- epilogue: acc[mf][nf] = {z_delta, z_select, z_in, z_gate}(m,n) ----
    // write outputs into LDS transpose tiles + in-register butterfly scan.
#pragma unroll
    for (int nf = 0; nf < 4; ++nf) {
        int dl = wc * 16 + nf * 4 + lk;        // n offset within 32
        float ean = ea[nt * 32 + dl];
        float A[4], S[4];
#pragma unroll
        for (int mf = 0; mf < 4; ++mf) {
            int t = wr * 64 + mf * 16 + l16;
            float zd = acc[mf][nf][0];
            float zs = acc[mf][nf][1];
            float zi = acc[mf][nf][2];
            float zg = acc[mf][nf][3];
            float e = __expf(zd);
            float delta = (zd > 15.f) ? zd : __logf(1.f + e);
            float dec = __expf(-delta * ean);
            float sel = 1.f / (1.f + __expf(-zs));
            float upd = delta * sel * zi;
            float g   = zg / (1.f + __expf(-zg));   // silu
            *(__half2*)(lds + (t * 36 + dl) * 4) = __floats2half2_rn(dec, upd);
            *(unsigned short*)(lds + 18432 + t * 80 + dl * 2) = f2bf(g);
            A[mf] = dec;
            S[mf] = upd;
        }
        // 16-lane butterfly compose over l16 (t-order = l16 within mf-block)
#pragma unroll
        for (int d = 1; d < 16; d <<= 1) {
            bool upper = (l16 & d);
#pragma unroll
            for (int mf = 0; mf < 4; ++mf) {
                float Ap = __shfl_xor(A[mf], d, 64);
                float Sp = __shfl_xor(S[mf], d, 64);
                float Se = upper ? Sp : S[mf];
                float Al = upper ? A[mf] : Ap;
                float Sl = upper ? S[mf] : Sp;
                S[mf] = fmaf(Al, Se, Sl);
                A[mf] = A[mf] * Ap;
            }
        }
        // in-thread compose across mf (t ascending: mf-blocks of 16)
        float cAe = A[0], cSe = S[0];
#pragma unroll
        for (int mf = 1; mf < 4; ++mf) {
            cSe = fmaf(A[mf], cSe, S[mf]);
            cAe *= A[mf];
        }
        if (l16 == 0) {
            int hc = mt * 2 + wr;              // = b*32 + (c*2 + wr)
            cA[hc * D_DIM + nt * 32 + dl] = cAe;
            cS[hc * D_DIM + nt * 32 + dl] = cSe;
        }
    }
    __syncthreads();

    // ---- coalesced writeback: full-line stores ----
    // du: 128 rows x 32 half2 (128B/row) -> 8 x 16B lanes cover a full line
    {
        size_t dub = (size_t)mbase * D_DIM + nt * 32;
#pragma unroll
        for (int i = 0; i < 4; ++i) {
            int slot = i * 256 + tid;
            int t = slot >> 3, seg = slot & 7;
            f32x4 v = *(const f32x4*)(lds + t * 144 + seg * 16);
            *(f32x4*)(du + dub + (size_t)t * D_DIM + seg * 4) = v;
        }
        // gate: 128 rows x 32 u16 (64B/row); nt-sibling (same XCD) completes line
#pragma unroll
        for (int i = 0; i < 2; ++i) {
            int slot = i * 256 + tid;
            int t = slot >> 2, seg = slot & 3;
            f32x4 v = *(const f32x4*)(lds + 18432 + t * 80 + seg * 16);
            *(f32x4*)(gate + dub + (size_t)t * D_DIM + seg * 8) = v;
        }
    }
}

// --------------------------- scan pass 2: half-chunk carries ---------------
__global__ __launch_bounds__(256) void scan2_kernel(
    const float* __restrict__ cA, const float* __restrict__ cS,
    float* __restrict__ carry)
{
    int b = blockIdx.x;
    int d = threadIdx.x;
    float s = 0.f;
    for (int c = 0; c < NCHUNK2; ++c) {
        int idx = (b * NCHUNK2 + c) * D_DIM + d;
        carry[idx] = s;                 // state entering half-chunk c
        s = fmaf(cA[idx], s, cS[idx]);
    }
}

// --------------------------- fused scan3 + out-projection ------------------
// block = (b, chunk of 128): scans 128 t-rows (full D), builds y tile in LDS
// (bf16, chunk-XOR-swizzled), then computes out[128 x 256] = y @ Wo^T.
__global__ __launch_bounds__(256) void scan_out_kernel(
    const __half2* __restrict__ du, const unsigned short* __restrict__ gate,
    const float* __restrict__ carry, const unsigned short* __restrict__ Wo,
    float* __restrict__ out)
{
    __shared__ unsigned short yls[128 * 256];   // 64 KB
    int b = blockIdx.x >> 4;
    int c = blockIdx.x & 15;
    int tid = threadIdx.x;

    // ---- phase 1: sequential scan, y -> LDS (swizzled 16B chunks) ----
    {
        int d = tid;
        size_t base = ((size_t)b * T_DIM + (size_t)c * CLEN) * D_DIM + d;
        float s = carry[(b * NCHUNK2 + c * 2) * D_DIM + d];
        int dlo = d & 7, dch = d >> 3;
#pragma unroll 4
        for (int t = 0; t < CLEN; ++t) {
            __half2 v = du[base + (size_t)t * D_DIM];
            float dc = __low2float(v);
            float up = __high2float(v);
            s = fmaf(dc, s, up);
            float g = bf2f(gate[base + (size_t)t * D_DIM]);
            int off = t * 256 + ((dch ^ (t & 7)) << 3) + dlo;
            yls[off] = f2bf(s * g);
        }
    }
    __syncthreads();

    // ---- phase 2: out-tile GEMM, A-frag = Wo rows (global), B-frag = y (LDS)
    int lane = tid & 63, wid = tid >> 6;
    int l16 = lane & 15;
    int lkc = lane >> 4;            // k-subgroup 0..3
    int m0 = (wid >> 1) * 64;
    size_t rbase = (size_t)b * T_DIM + (size_t)c * CLEN;
    int r0 = lkc * 4;

    for (int nblk = 0; nblk < 2; ++nblk) {
        int n0 = (wid & 1) * 64 + nblk * 128;
        f32x4 acc[4][4] = {};
        for (int ks = 0; ks < 8; ++ks) {
            int kb = ks * 32 + lkc * 8;
            s16x8 yf[4];
#pragma unroll
            for (int mf = 0; mf < 4; ++mf) {
                int row = m0 + mf * 16 + l16;
                int chunk = (ks * 4 + lkc) ^ (row & 7);
                yf[mf] = *(const s16x8*)&yls[row * 256 + chunk * 8];
            }
#pragma unroll
            for (int nf = 0; nf < 4; ++nf) {
                s16x8 wfr = *(const s16x8*)(Wo + (size_t)(n0 + nf * 16 + l16) * D_DIM + kb);
#pragma unroll
                for (int mf = 0; mf < 4; ++mf)
                    acc[mf][nf] = __builtin_amdgcn_mfma_f32_16x16x32_bf16(
                        wfr, yf[mf], acc[mf][nf], 0, 0, 0);
            }
        }
        // D col = lane&15 = y row; D rows = n (4 consecutive) -> float4 stores
#pragma unroll
        for (int mf = 0; mf < 4; ++mf) {
            size_t rowg = rbase + m0 + mf * 16 + l16;
#pragma unroll
            for (int nf = 0; nf < 4; ++nf) {
                int n = n0 + nf * 16 + r0;
                *(f32x4*)(out + rowg * D_DIM + n) = acc[mf][nf];
            }
        }
    }
}

// ---------------------------------------------------------------------------
extern "C" void kernel_launch(void* const* d_in, const int* in_sizes, int n_in,
                              void* d_out, int out_size, void* d_ws, size_t ws_size,
                              hipStream_t stream)
{
    const float* x        = (const float*)d_in[0];
    const float* W_in     = (const float*)d_in[1];
    const float* W_select = (const float*)d_in[2];
    const float* W_gate   = (const float*)d_in[3];
    const float* W_out    = (const float*)d_in[4];
    const float* W_delta  = (const float*)d_in[5];
    const float* log_a    = (const float*)d_in[6];
    float* out = (float*)d_out;

    char* ws = (char*)d_ws;
    const size_t MB = 1ull << 20;
    unsigned short* Wb    = (unsigned short*)(ws);               // 640 KB
    float*          ea    = (float*)(ws + 655360);               // 1 KB
    unsigned short* xb    = (unsigned short*)(ws + 1 * MB);      // 128 MB
    __half2*        du    = (__half2*)(ws + 129 * MB);           // 256 MB
    unsigned short* gate  = (unsigned short*)(ws + 385 * MB);    // 128 MB
    float*          cA    = (float*)(ws + 513 * MB);             // 4 MB
    float*          cS    = (float*)(ws + 517 * MB);             // 4 MB
    float*          carry = (float*)(ws + 521 * MB);             // 4 MB
    // total: 525 MB

    prep_kernel<<<1281, 256, 0, stream>>>(W_in, W_select, W_gate, W_out,
                                          W_delta, log_a, Wb, ea);
    xcast_kernel<<<32768, 256, 0, stream>>>(x, xb);
    gemm_fused_kernel<<<16384, 256, 0, stream>>>(xb, Wb, ea, du, gate, cA, cS);
    scan2_kernel<<<B_DIM, 256, 0, stream>>>(cA, cS, carry);
    scan_out_kernel<<<B_DIM * NCHUNK2 / 2, 256, 0, stream>>>(du, gate, carry,
                                                             Wb + 4 * 65536, out);
}